// Round 2
// baseline (1784.575 us; speedup 1.0000x reference)
//
#include <hip/hip_runtime.h>
#include <math.h>

#define B_ 2
#define T_ 2048
#define C_ 1024
#define H_ 16
#define D_ 64
#define M_ (B_*T_)          // 4096
#define HEADSZ (T_*D_)      // 131072 floats per (b,h)
#define QKVSZ (B_*H_*T_*D_) // 4194304 floats per tensor (Q or K or V)

// ---------------------------------------------------------------------------
// GEMM: C[m][n] = sum_k A[m][k]*W[n][k] + bias[n]
// A: [M][K] row-major, W: [N][K] row-major (torch Linear weight layout).
// BM=BN=128, BK=8, 256 threads, 8x8 per-thread microtile.
// WRITE_MODE 0: scatter into QKV [s][b][h][t][d] at `out`; 1: row-major [M][N].
// ---------------------------------------------------------------------------
template <int WRITE_MODE>
__global__ __launch_bounds__(256) void gemm_kernel(const float* __restrict__ A,
                                                   const float* __restrict__ W,
                                                   const float* __restrict__ bias,
                                                   float* __restrict__ out,
                                                   int Kdim, int Ndim, int nbm) {
    __shared__ __align__(16) float As[8][132];  // transposed: As[k][m], pad 132
    __shared__ __align__(16) float Bs[8][132];  // transposed: Bs[k][n]

    const int tid = threadIdx.x;
    const int bm = blockIdx.x % nbm;     // m-tile
    const int bn = blockIdx.x / nbm;     // n-tile
    const int r = tid >> 1;              // 0..127 staging row
    const int f = tid & 1;               // 0..1 float4 column
    const int tx = tid & 15;             // compute col group
    const int ty = tid >> 4;             // compute row group

    float acc[8][8];
#pragma unroll
    for (int u = 0; u < 8; ++u)
#pragma unroll
        for (int v = 0; v < 8; ++v) acc[u][v] = 0.f;

    const float* Arow = A + (size_t)(bm * 128 + r) * Kdim + f * 4;
    const float* Wrow = W + (size_t)(bn * 128 + r) * Kdim + f * 4;

    for (int k0 = 0; k0 < Kdim; k0 += 8) {
        const float4 a4 = *(const float4*)(Arow + k0);
        const float4 w4 = *(const float4*)(Wrow + k0);
        __syncthreads();  // previous-tile reads done before overwrite
        As[f * 4 + 0][r] = a4.x; As[f * 4 + 1][r] = a4.y;
        As[f * 4 + 2][r] = a4.z; As[f * 4 + 3][r] = a4.w;
        Bs[f * 4 + 0][r] = w4.x; Bs[f * 4 + 1][r] = w4.y;
        Bs[f * 4 + 2][r] = w4.z; Bs[f * 4 + 3][r] = w4.w;
        __syncthreads();
#pragma unroll
        for (int kk = 0; kk < 8; ++kk) {
            const float4 a0 = *(const float4*)&As[kk][ty * 8];
            const float4 a1 = *(const float4*)&As[kk][ty * 8 + 4];
            const float4 b0 = *(const float4*)&Bs[kk][tx * 8];
            const float4 b1 = *(const float4*)&Bs[kk][tx * 8 + 4];
            const float av[8] = {a0.x, a0.y, a0.z, a0.w, a1.x, a1.y, a1.z, a1.w};
            const float bv[8] = {b0.x, b0.y, b0.z, b0.w, b1.x, b1.y, b1.z, b1.w};
#pragma unroll
            for (int u = 0; u < 8; ++u)
#pragma unroll
                for (int v = 0; v < 8; ++v) acc[u][v] = fmaf(av[u], bv[v], acc[u][v]);
        }
    }

#pragma unroll
    for (int u = 0; u < 8; ++u) {
        const int m = bm * 128 + ty * 8 + u;
#pragma unroll
        for (int v = 0; v < 8; ++v) {
            const int n = bn * 128 + tx * 8 + v;
            const float val = acc[u][v] + bias[n];
            if (WRITE_MODE == 0) {
                // n -> (s, h, d); m -> (b, t); write [s][b][h][t][d]
                const int s = n >> 10;
                const int h = (n >> 6) & 15;
                const int d = n & 63;
                const int b = m >> 11;
                const int t = m & 2047;
                out[(size_t)s * QKVSZ + ((size_t)(b * H_ + h) * T_ + t) * D_ + d] = val;
            } else {
                out[(size_t)m * Ndim + n] = val;
            }
        }
    }
}

// ---------------------------------------------------------------------------
// Flash attention, fp32. Block = 256 threads = 4 waves; 32 q-rows per block
// (8 per wave). Q read via wave-uniform scalar loads (s_load, scalar cache);
// K staged transposed (Kt[d][j], +1 pad -> conflict-free lane-j reads);
// V natural; P via per-wave LDS broadcast reads. Next K/V tile prefetched
// into registers during compute (T14 async-stage). Grid indexed qt*32+bh so
// XCD = bh%8 -> per-XCD live KV working set ~4MB (fits its L2).
// ---------------------------------------------------------------------------
__global__ __launch_bounds__(256) void attn_kernel(const float* __restrict__ ws,
                                                   float* __restrict__ AO) {
    const float* Qg = ws;
    const float* Kg = ws + QKVSZ;
    const float* Vg = ws + 2 * QKVSZ;

    __shared__ __align__(16) float Kt[64][65];   // Kt[d][j]
    __shared__ __align__(16) float Vs[64][64];   // Vs[j][d]
    __shared__ __align__(16) float Pl[4][8][64]; // per-wave P rows

    const int tid = threadIdx.x;
    const int lane = tid & 63;
    const int w = tid >> 6;     // wave 0..3
    const int rr = w;           // staging row offset 0..3
    const int c = lane;

    const int bh = blockIdx.x & 31;   // head index -> XCD = bh%8
    const int qt = blockIdx.x >> 5;   // q-tile of 32 rows, 0..63

    const float* Kb = Kg + (size_t)bh * HEADSZ;
    const float* Vb = Vg + (size_t)bh * HEADSZ;

    // wave-uniform Q base (readfirstlane forces SGPR -> s_load for Q reads)
    const int wu = __builtin_amdgcn_readfirstlane(w);
    const float* Qw = Qg + (size_t)bh * HEADSZ + ((size_t)(qt * 32 + wu * 8)) * 64;

    float m[8], l[8], O[8];
#pragma unroll
    for (int r = 0; r < 8; ++r) { m[r] = -INFINITY; l[r] = 0.f; O[r] = 0.f; }

    // preload K/V tile 0 into registers
    float kreg[16], vreg[16];
#pragma unroll
    for (int it = 0; it < 16; ++it) {
        const int row = it * 4 + rr;
        kreg[it] = Kb[row * 64 + c];
        vreg[it] = Vb[row * 64 + c];
    }

    for (int kt = 0; kt < 32; ++kt) {
        __syncthreads();  // all reads of previous tile done
#pragma unroll
        for (int it = 0; it < 16; ++it) {
            const int row = it * 4 + rr;  // 0..63
            Kt[c][row] = kreg[it];
            Vs[row][c] = vreg[it];
        }
        __syncthreads();

        // prefetch next tile into registers; latency hides under compute
        if (kt < 31) {
            const float* Kn = Kb + (size_t)(kt + 1) * 64 * 64;
            const float* Vn = Vb + (size_t)(kt + 1) * 64 * 64;
#pragma unroll
            for (int it = 0; it < 16; ++it) {
                const int row = it * 4 + rr;
                kreg[it] = Kn[row * 64 + c];
                vreg[it] = Vn[row * 64 + c];
            }
        }

        // ---- scores: lane = key j; 8 q-rows per wave; Q via scalar loads
        float s[8];
#pragma unroll
        for (int r = 0; r < 8; ++r) s[r] = 0.f;
#pragma unroll
        for (int d0 = 0; d0 < 64; d0 += 4) {
            const float k0 = Kt[d0 + 0][lane];
            const float k1 = Kt[d0 + 1][lane];
            const float k2 = Kt[d0 + 2][lane];
            const float k3 = Kt[d0 + 3][lane];
#pragma unroll
            for (int r = 0; r < 8; ++r) {
                const float4 q = *(const float4*)(Qw + r * 64 + d0);  // uniform -> s_load_dwordx4
                s[r] = fmaf(q.x, k0, fmaf(q.y, k1, fmaf(q.z, k2, fmaf(q.w, k3, s[r]))));
            }
        }
#pragma unroll
        for (int r = 0; r < 8; ++r) s[r] *= 0.125f;  // 1/sqrt(64)

        // ---- online softmax (64-lane butterflies)
        float p[8];
#pragma unroll
        for (int r = 0; r < 8; ++r) {
            float t = s[r];
#pragma unroll
            for (int off = 32; off; off >>= 1) t = fmaxf(t, __shfl_xor(t, off));
            const float mn = fmaxf(m[r], t);
            const float al = __expf(m[r] - mn);
            m[r] = mn;
            p[r] = __expf(s[r] - mn);
            float u = p[r];
#pragma unroll
            for (int off = 32; off; off >>= 1) u += __shfl_xor(u, off);
            l[r] = l[r] * al + u;
            O[r] *= al;
        }

#pragma unroll
        for (int r = 0; r < 8; ++r) Pl[w][r][lane] = p[r];
        __syncthreads();  // P visible (also orders wave-internal LDS)

        // ---- PV: lane = d
#pragma unroll
        for (int j0 = 0; j0 < 64; j0 += 4) {
            const float v0 = Vs[j0 + 0][lane];
            const float v1 = Vs[j0 + 1][lane];
            const float v2 = Vs[j0 + 2][lane];
            const float v3 = Vs[j0 + 3][lane];
#pragma unroll
            for (int r = 0; r < 8; ++r) {
                const float4 pb = *(const float4*)&Pl[w][r][j0];
                O[r] = fmaf(pb.x, v0, fmaf(pb.y, v1, fmaf(pb.z, v2, fmaf(pb.w, v3, O[r]))));
            }
        }
    }

    // write attn output into [B][T][C] layout for the out-proj GEMM
    const int b = bh >> 4, h = bh & 15;
    const int q0 = qt * 32 + w * 8;
    float* base = AO + ((size_t)(b * T_ + q0) * C_) + h * 64 + lane;
#pragma unroll
    for (int r = 0; r < 8; ++r) base[(size_t)r * C_] = O[r] / l[r];
}

extern "C" void kernel_launch(void* const* d_in, const int* in_sizes, int n_in,
                              void* d_out, int out_size, void* d_ws, size_t ws_size,
                              hipStream_t stream) {
    const float* x     = (const float*)d_in[0];
    const float* W_qkv = (const float*)d_in[1];
    const float* b_qkv = (const float*)d_in[2];
    const float* W_o   = (const float*)d_in[3];
    const float* b_o   = (const float*)d_in[4];
    float* out = (float*)d_out;
    float* ws  = (float*)d_ws;
    float* AO  = ws + (size_t)3 * QKVSZ;  // attention output [B][T][C]

    // 1) QKV projection: M=4096, N=3072, K=1024 -> scatter to Q/K/V in ws
    gemm_kernel<0><<<dim3((M_ / 128) * (3 * C_ / 128)), dim3(256), 0, stream>>>(
        x, W_qkv, b_qkv, ws, C_, 3 * C_, M_ / 128);

    // 2) flash attention: 32 heads x 64 q-tiles; blk = qt*32 + bh
    attn_kernel<<<dim3(B_ * H_ * (T_ / 32)), dim3(256), 0, stream>>>(ws, AO);

    // 3) output projection: M=4096, N=1024, K=1024
    gemm_kernel<1><<<dim3((M_ / 128) * (C_ / 128)), dim3(256), 0, stream>>>(
        AO, W_o, b_o, out, C_, C_, M_ / 128);
}

// Round 4
// 669.990 us; speedup vs baseline: 2.6636x; 2.6636x over previous
//
#include <hip/hip_runtime.h>
#include <math.h>

#define B_ 2
#define T_ 2048
#define C_ 1024
#define H_ 16
#define D_ 64
#define M_ (B_*T_)          // 4096
#define QKVSZ (B_*H_*T_*D_) // 4194304 elements per tensor

typedef _Float16 f16;
typedef _Float16 f16x8 __attribute__((ext_vector_type(8)));
typedef float f32x4 __attribute__((ext_vector_type(4)));

// ---------------------------------------------------------------------------
// GEMM: C[m][n] = sum_k A[m][k]*W[n][k] + bias[n]
// A: [M][K] row-major, W: [N][K] row-major (torch Linear weight layout).
// BM=BN=128, BK=8, 256 threads, 8x8 per-thread microtile.
// WRITE_MODE 0: emit f16 Q (prescaled 1/8), f16 K (tile-swizzled),
//               f16 V^T (tile-swizzled) into ws for the MFMA attention.
// WRITE_MODE 1: fp32 row-major [M][N] (final output).
// ---------------------------------------------------------------------------
template <int WRITE_MODE>
__global__ __launch_bounds__(256) void gemm_kernel(const float* __restrict__ A,
                                                   const float* __restrict__ W,
                                                   const float* __restrict__ bias,
                                                   void* __restrict__ out,
                                                   int Kdim, int Ndim, int nbm) {
    __shared__ __align__(16) float As[8][132];  // transposed: As[k][m]
    __shared__ __align__(16) float Bs[8][132];  // transposed: Bs[k][n]

    const int tid = threadIdx.x;
    const int bm = blockIdx.x % nbm;
    const int bn = blockIdx.x / nbm;
    const int r = tid >> 1;
    const int f = tid & 1;
    const int tx = tid & 15;
    const int ty = tid >> 4;

    float acc[8][8];
#pragma unroll
    for (int u = 0; u < 8; ++u)
#pragma unroll
        for (int v = 0; v < 8; ++v) acc[u][v] = 0.f;

    const float* Arow = A + (size_t)(bm * 128 + r) * Kdim + f * 4;
    const float* Wrow = W + (size_t)(bn * 128 + r) * Kdim + f * 4;

    for (int k0 = 0; k0 < Kdim; k0 += 8) {
        const float4 a4 = *(const float4*)(Arow + k0);
        const float4 w4 = *(const float4*)(Wrow + k0);
        __syncthreads();
        As[f * 4 + 0][r] = a4.x; As[f * 4 + 1][r] = a4.y;
        As[f * 4 + 2][r] = a4.z; As[f * 4 + 3][r] = a4.w;
        Bs[f * 4 + 0][r] = w4.x; Bs[f * 4 + 1][r] = w4.y;
        Bs[f * 4 + 2][r] = w4.z; Bs[f * 4 + 3][r] = w4.w;
        __syncthreads();
#pragma unroll
        for (int kk = 0; kk < 8; ++kk) {
            const float4 a0 = *(const float4*)&As[kk][ty * 8];
            const float4 a1 = *(const float4*)&As[kk][ty * 8 + 4];
            const float4 b0 = *(const float4*)&Bs[kk][tx * 8];
            const float4 b1 = *(const float4*)&Bs[kk][tx * 8 + 4];
            const float av[8] = {a0.x, a0.y, a0.z, a0.w, a1.x, a1.y, a1.z, a1.w};
            const float bv[8] = {b0.x, b0.y, b0.z, b0.w, b1.x, b1.y, b1.z, b1.w};
#pragma unroll
            for (int u = 0; u < 8; ++u)
#pragma unroll
                for (int v = 0; v < 8; ++v) acc[u][v] = fmaf(av[u], bv[v], acc[u][v]);
        }
    }

#pragma unroll
    for (int u = 0; u < 8; ++u) {
        const int m = bm * 128 + ty * 8 + u;
#pragma unroll
        for (int v = 0; v < 8; ++v) {
            const int n = bn * 128 + tx * 8 + v;
            const float val = acc[u][v] + bias[n];
            if (WRITE_MODE == 0) {
                // n -> (s,h,d); m -> (b,t)
                const int s = n >> 10;
                const int h = (n >> 6) & 15;
                const int d = n & 63;
                const int b = m >> 11;
                const int t = m & 2047;
                const int bh = b * H_ + h;
                f16* base = (f16*)out;
                if (s == 0) {
                    // Q: plain [bh][t][d], prescaled by 1/sqrt(64)
                    base[((size_t)(bh * T_ + t)) * 64 + d] = (f16)(val * 0.125f);
                } else {
                    const int tile = t >> 6, row = t & 63;
                    if (s == 1) {
                        // K: [bh][tile][row=key][chunk'^swz][d&7]
                        const int ch = (d >> 3) ^ (row & 7);
                        base[(size_t)QKVSZ +
                             ((size_t)((bh * 32 + tile) * 64 + row)) * 64 + ch * 8 + (d & 7)] = (f16)val;
                    } else {
                        // V^T: [bh][tile][drow=d][chunk'^swz][j&7], j = row
                        const int cj = (row >> 3) ^ (d & 7);
                        base[(size_t)(2 * QKVSZ) +
                             ((size_t)((bh * 32 + tile) * 64 + d)) * 64 + cj * 8 + (row & 7)] = (f16)val;
                    }
                }
            } else {
                ((float*)out)[(size_t)m * Ndim + n] = val;
            }
        }
    }
}

// ---------------------------------------------------------------------------
// MFMA flash attention (f16 in, fp32 accum). Block = 4 waves, 64 q-rows
// (16/wave). K-tile = 64 keys. Single LDS buffer, register prefetch of next
// tile. All LDS fragment reads use chunk-XOR swizzle (<=2-way = free).
// Softmax: per-tile row-max via 16-lane butterfly; row-sum kept lane-partial,
// reduced once at the end. P transposed through wave-private swizzled LDS.
// Grid: blk = qt*32 + bh  ->  XCD = bh%8 (KV working set ~2MB/XCD, L2-fits).
// ---------------------------------------------------------------------------
__global__ __launch_bounds__(256) void attn_mfma(const f16* __restrict__ Qf,
                                                 const f16* __restrict__ Kf,
                                                 const f16* __restrict__ Vf,
                                                 float* __restrict__ AO) {
    __shared__ __align__(16) f16 Kh[64 * 64];     // [key][d] swizzled
    __shared__ __align__(16) f16 Vt[64 * 64];     // [d][j]  swizzled
    __shared__ __align__(16) f16 Pl[4][16 * 64];  // per-wave [qr][j] swizzled

    const int tid = threadIdx.x;
    const int lane = tid & 63;
    const int w = tid >> 6;
    const int g = lane >> 4;   // k-group 0..3
    const int c = lane & 15;   // row/col within fragment

    const int bh = blockIdx.x & 31;
    const int qt = blockIdx.x >> 5;   // 0..31 (64 q-rows each)

    // Q A-fragments: lane holds Q[w*16+c][g*8 .. g*8+7] (+32 for kstep 1)
    const f16* Qp = Qf + ((size_t)(bh * T_ + qt * 64 + w * 16 + c)) * 64 + g * 8;
    const f16x8 qa0 = *(const f16x8*)(Qp);
    const f16x8 qa1 = *(const f16x8*)(Qp + 32);

    f32x4 o[4];
    float mrow[4], lsum[4];
#pragma unroll
    for (int i = 0; i < 4; ++i) {
        f32x4 z = {0.f, 0.f, 0.f, 0.f};
        o[i] = z;
        mrow[i] = -INFINITY;
        lsum[i] = 0.f;
    }

    const f16* Ktile = Kf + (size_t)bh * 32 * 4096;
    const f16* Vtile = Vf + (size_t)bh * 32 * 4096;

    // each thread stages two 16B chunks of K and of V^T (linear copy)
    const int soff0 = (w * 128 + lane) * 8;       // element offsets
    const int soff1 = (w * 128 + 64 + lane) * 8;

    uint4 kr0 = *(const uint4*)(Ktile + soff0);
    uint4 kr1 = *(const uint4*)(Ktile + soff1);
    uint4 vr0 = *(const uint4*)(Vtile + soff0);
    uint4 vr1 = *(const uint4*)(Vtile + soff1);

    f16* const Pw = Pl[w];

    for (int kt = 0; kt < 32; ++kt) {
        __syncthreads();  // previous tile fully consumed
        *(uint4*)(Kh + soff0) = kr0;
        *(uint4*)(Kh + soff1) = kr1;
        *(uint4*)(Vt + soff0) = vr0;
        *(uint4*)(Vt + soff1) = vr1;
        __syncthreads();  // tile staged

        if (kt < 31) {  // prefetch next tile; latency hides under compute
            const f16* Kn = Ktile + (size_t)(kt + 1) * 4096;
            const f16* Vn = Vtile + (size_t)(kt + 1) * 4096;
            kr0 = *(const uint4*)(Kn + soff0);
            kr1 = *(const uint4*)(Kn + soff1);
            vr0 = *(const uint4*)(Vn + soff0);
            vr1 = *(const uint4*)(Vn + soff1);
        }

        // ---- QK^T: S[qr][j], 8 MFMAs
        f32x4 s[4];
#pragma unroll
        for (int jt = 0; jt < 4; ++jt) {
            f32x4 z = {0.f, 0.f, 0.f, 0.f};
            s[jt] = z;
        }
#pragma unroll
        for (int ks = 0; ks < 2; ++ks) {
            const f16x8 qa = ks ? qa1 : qa0;
#pragma unroll
            for (int jt = 0; jt < 4; ++jt) {
                const int row = jt * 16 + c;  // key index
                const f16x8 kb = *(const f16x8*)(Kh + row * 64 + (((ks * 4 + g) ^ (row & 7)) * 8));
                s[jt] = __builtin_amdgcn_mfma_f32_16x16x32_f16(qa, kb, s[jt], 0, 0, 0);
            }
        }

        // ---- online softmax (rows = g*4+r, stats shared across the 16 c-lanes)
        float al[4];
#pragma unroll
        for (int r = 0; r < 4; ++r) {
            float mx = fmaxf(fmaxf(s[0][r], s[1][r]), fmaxf(s[2][r], s[3][r]));
            mx = fmaxf(mx, __shfl_xor(mx, 1));
            mx = fmaxf(mx, __shfl_xor(mx, 2));
            mx = fmaxf(mx, __shfl_xor(mx, 4));
            mx = fmaxf(mx, __shfl_xor(mx, 8));
            const float mn = fmaxf(mrow[r], mx);
            al[r] = __expf(mrow[r] - mn);
            mrow[r] = mn;
            float ps = 0.f;
#pragma unroll
            for (int jt = 0; jt < 4; ++jt) {
                const float p = __expf(s[jt][r] - mn);
                s[jt][r] = p;
                ps += p;
            }
            lsum[r] = lsum[r] * al[r] + ps;  // lane-partial; reduced at end
        }

        // ---- P -> wave-private LDS (f16, swizzled) for the A-operand transpose
#pragma unroll
        for (int jt = 0; jt < 4; ++jt)
#pragma unroll
            for (int r = 0; r < 4; ++r) {
                const int row = g * 4 + r;                       // q-row
                const int ch = (jt * 2 + (c >> 3)) ^ (row & 7);  // swizzled 16B chunk
                Pw[row * 64 + ch * 8 + (c & 7)] = (f16)s[jt][r];
            }
        asm volatile("s_waitcnt lgkmcnt(0)" ::: "memory");  // wave-internal P visible

        // ---- rescale O, then PV: O[qr][d] += P*V, 8 MFMAs
#pragma unroll
        for (int dt = 0; dt < 4; ++dt)
#pragma unroll
            for (int r = 0; r < 4; ++r) o[dt][r] *= al[r];

#pragma unroll
        for (int ks = 0; ks < 2; ++ks) {
            const f16x8 pa = *(const f16x8*)(Pw + c * 64 + (((ks * 4 + g) ^ (c & 7)) * 8));
#pragma unroll
            for (int dt = 0; dt < 4; ++dt) {
                const int row = dt * 16 + c;  // d index
                const f16x8 vb = *(const f16x8*)(Vt + row * 64 + (((ks * 4 + g) ^ (row & 7)) * 8));
                o[dt] = __builtin_amdgcn_mfma_f32_16x16x32_f16(pa, vb, o[dt], 0, 0, 0);
            }
        }
    }

    // final row-sum reduce + normalize + write AO [B][T][C] fp32
#pragma unroll
    for (int r = 0; r < 4; ++r) {
        float v = lsum[r];
        v += __shfl_xor(v, 1);
        v += __shfl_xor(v, 2);
        v += __shfl_xor(v, 4);
        v += __shfl_xor(v, 8);
        lsum[r] = 1.f / v;
    }
    const int b = bh >> 4, h = bh & 15;
#pragma unroll
    for (int dt = 0; dt < 4; ++dt)
#pragma unroll
        for (int r = 0; r < 4; ++r) {
            const int row = qt * 64 + w * 16 + g * 4 + r;
            AO[((size_t)(b * T_ + row)) * C_ + h * 64 + dt * 16 + c] = o[dt][r] * lsum[r];
        }
}

extern "C" void kernel_launch(void* const* d_in, const int* in_sizes, int n_in,
                              void* d_out, int out_size, void* d_ws, size_t ws_size,
                              hipStream_t stream) {
    const float* x     = (const float*)d_in[0];
    const float* W_qkv = (const float*)d_in[1];
    const float* b_qkv = (const float*)d_in[2];
    const float* W_o   = (const float*)d_in[3];
    const float* b_o   = (const float*)d_in[4];

    f16* Qf = (f16*)d_ws;                       // [32][2048][64] f16
    f16* Kf = Qf + QKVSZ;                       // swizzled tiles
    f16* Vf = Kf + QKVSZ;                       // transposed swizzled tiles
    float* AO = (float*)((char*)d_ws + (size_t)3 * QKVSZ * sizeof(f16));  // [B][T][C] fp32

    // 1) QKV projection (fp32 compute) -> f16 Q/K/V^T in attention layouts
    gemm_kernel<0><<<dim3((M_ / 128) * (3 * C_ / 128)), dim3(256), 0, stream>>>(
        x, W_qkv, b_qkv, (void*)Qf, C_, 3 * C_, M_ / 128);

    // 2) MFMA flash attention: 32 q-tiles x 32 heads
    attn_mfma<<<dim3(32 * 32), dim3(256), 0, stream>>>(Qf, Kf, Vf, AO);

    // 3) output projection (fp32): M=4096, N=1024, K=1024
    gemm_kernel<1><<<dim3((M_ / 128) * (C_ / 128)), dim3(256), 0, stream>>>(
        AO, W_o, b_o, (void*)d_out, C_, C_, M_ / 128);
}

// Round 9
// 241.134 us; speedup vs baseline: 7.4008x; 2.7785x over previous
//
#include <hip/hip_runtime.h>
#include <math.h>

#define B_ 2
#define T_ 2048
#define C_ 1024
#define H_ 16
#define M_ (B_*T_)            // 4096
#define QKVSZ (B_*H_*T_*64)   // 4194304 elements per tensor

typedef _Float16 f16;
typedef _Float16 f16x8 __attribute__((ext_vector_type(8)));
typedef float f32x4 __attribute__((ext_vector_type(4)));

// async global->LDS, 16B per lane; LDS dest is wave-uniform base + lane*16
#define GLL16(g, l) __builtin_amdgcn_global_load_lds(                     \
    (const __attribute__((address_space(1))) void*)(g),                   \
    (__attribute__((address_space(3))) void*)(l), 16, 0, 0)

// Barrier with HW-enforced drain of all outstanding VMEM + LDS ops, pinned
// against compiler reordering. Closes the WAR race: without the explicit
// lgkmcnt(0)+sched_barrier, hipcc can sink MFMAs (register-only) below
// s_barrier, leaving ds_reads in flight across it; a warm (L2-hit)
// global_load_lds then clobbers LDS before those reads are serviced.
// (Round-8 symptom: cold first launch correct, warm replays diverged.)
#define DRAIN_SYNC() do {                                                 \
    asm volatile("s_waitcnt vmcnt(0) lgkmcnt(0)" ::: "memory");           \
    __builtin_amdgcn_sched_barrier(0);                                    \
    __syncthreads();                                                      \
} while (0)

// ---------------------------------------------------------------------------
// fp32 -> f16 cast prepass: x (4M), W_qkv (3M), W_o (1M). 2048 elems/block.
// ---------------------------------------------------------------------------
__global__ __launch_bounds__(256) void cvt_kernel(const float* __restrict__ x,
                                                  const float* __restrict__ wq,
                                                  const float* __restrict__ wo,
                                                  f16* __restrict__ xf,
                                                  f16* __restrict__ wqf,
                                                  f16* __restrict__ wof) {
    const int b = blockIdx.x;
    const float* src;
    f16* dst;
    size_t off;
    if (b < 2048)      { src = x;  dst = xf;  off = (size_t)b * 2048; }
    else if (b < 3584) { src = wq; dst = wqf; off = (size_t)(b - 2048) * 2048; }
    else               { src = wo; dst = wof; off = (size_t)(b - 3584) * 2048; }
    const size_t e = off + (size_t)threadIdx.x * 8;
    const float4 v0 = *(const float4*)(src + e);
    const float4 v1 = *(const float4*)(src + e + 4);
    f16x8 r = {(f16)v0.x, (f16)v0.y, (f16)v0.z, (f16)v0.w,
               (f16)v1.x, (f16)v1.y, (f16)v1.z, (f16)v1.w};
    *(f16x8*)(dst + e) = r;
}

// ---------------------------------------------------------------------------
// f16 MFMA GEMM (m97 2-phase structure): C[m][n] = sum_k A[m][k]*W[n][k]+bias.
// A:[M][1024] f16 row-major, W:[N][1024] f16 row-major. BM=BN=128, BK=32,
// 4 waves (2x2), wave tile 64x64 = 4x4 fragments of 16x16x32. Double-buffered
// LDS staged via global_load_lds width-16. fp32 accumulate, fp32 bias.
// WRITE_MODE 0: scatter f16 Q (prescaled 1/8) / K (swizzled) / V^T (swizzled).
// WRITE_MODE 1: fp32 row-major [M][1024].
// ---------------------------------------------------------------------------
template <int WRITE_MODE>
__global__ __launch_bounds__(256) void gemm_f16(const f16* __restrict__ Af,
                                                const f16* __restrict__ Bf,
                                                const float* __restrict__ bias,
                                                void* __restrict__ out,
                                                int nbm) {
    __shared__ __align__(16) f16 At[2][128 * 32];
    __shared__ __align__(16) f16 Bt[2][128 * 32];

    const int tid = threadIdx.x;
    const int l = tid & 63;
    const int w = tid >> 6;
    const int c = l & 15, g = l >> 4;
    const int wr = w >> 1, wc = w & 1;
    const int bm = blockIdx.x % nbm, bn = blockIdx.x / nbm;

    // staging: wave w covers tile rows [w*32, w*32+32); lane l -> row w*32+(l>>2), k (l&3)*8
    const f16* Ag = Af + (size_t)(bm * 128 + w * 32 + (l >> 2)) * 1024 + (l & 3) * 8;
    const f16* Bg = Bf + (size_t)(bn * 128 + w * 32 + (l >> 2)) * 1024 + (l & 3) * 8;

    f32x4 acc[4][4];
#pragma unroll
    for (int mt = 0; mt < 4; ++mt)
#pragma unroll
        for (int nt = 0; nt < 4; ++nt) {
            f32x4 z = {0.f, 0.f, 0.f, 0.f};
            acc[mt][nt] = z;
        }

    // prologue: stage K-tile 0 into buffer 0
    GLL16(Ag,         &At[0][w * 1024]);
    GLL16(Ag + 16384, &At[0][w * 1024 + 512]);   // +16 rows
    GLL16(Bg,         &Bt[0][w * 1024]);
    GLL16(Bg + 16384, &Bt[0][w * 1024 + 512]);
    DRAIN_SYNC();

    int cur = 0;
    for (int ks = 0; ks < 32; ++ks) {
        if (ks < 31) {  // prefetch next K-tile into the other buffer
            const int k0 = (ks + 1) * 32;
            GLL16(Ag + k0,         &At[cur ^ 1][w * 1024]);
            GLL16(Ag + k0 + 16384, &At[cur ^ 1][w * 1024 + 512]);
            GLL16(Bg + k0,         &Bt[cur ^ 1][w * 1024]);
            GLL16(Bg + k0 + 16384, &Bt[cur ^ 1][w * 1024 + 512]);
        }
        const f16* Acur = At[cur];
        const f16* Bcur = Bt[cur];
        f16x8 af[4];
#pragma unroll
        for (int mt = 0; mt < 4; ++mt)
            af[mt] = *(const f16x8*)(Acur + (wr * 64 + mt * 16 + c) * 32 + g * 8);
#pragma unroll
        for (int nt = 0; nt < 4; ++nt) {
            const f16x8 bfr = *(const f16x8*)(Bcur + (wc * 64 + nt * 16 + c) * 32 + g * 8);
#pragma unroll
            for (int mt = 0; mt < 4; ++mt)
                acc[mt][nt] = __builtin_amdgcn_mfma_f32_16x16x32_f16(af[mt], bfr, acc[mt][nt], 0, 0, 0);
        }
        DRAIN_SYNC();  // all loads landed + all reads of cur complete before reuse
        cur ^= 1;
    }

    // epilogue: C/D layout col=lane&15, row=(lane>>4)*4+reg
#pragma unroll
    for (int mt = 0; mt < 4; ++mt)
#pragma unroll
        for (int nt = 0; nt < 4; ++nt)
#pragma unroll
            for (int r = 0; r < 4; ++r) {
                const int m = bm * 128 + wr * 64 + mt * 16 + g * 4 + r;
                const int n = bn * 128 + wc * 64 + nt * 16 + c;
                const float val = acc[mt][nt][r] + bias[n];
                if (WRITE_MODE == 0) {
                    const int s = n >> 10, h = (n >> 6) & 15, d = n & 63;
                    const int b = m >> 11, t = m & 2047;
                    const int bh = b * H_ + h;
                    f16* base = (f16*)out;
                    if (s == 0) {
                        // Q: [bh][t][d], prescaled 1/sqrt(64)
                        base[((size_t)(bh * T_ + t)) * 64 + d] = (f16)(val * 0.125f);
                    } else {
                        const int tile = t >> 6, row = t & 63;
                        if (s == 1) {
                            // K: [bh][tile][key][chunk^swz][d&7]
                            const int ch = (d >> 3) ^ (row & 7);
                            base[(size_t)QKVSZ +
                                 ((size_t)((bh * 32 + tile) * 64 + row)) * 64 + ch * 8 + (d & 7)] = (f16)val;
                        } else {
                            // V^T: [bh][tile][d][chunk^swz][j&7]
                            const int cj = (row >> 3) ^ (d & 7);
                            base[(size_t)(2 * QKVSZ) +
                                 ((size_t)((bh * 32 + tile) * 64 + d)) * 64 + cj * 8 + (row & 7)] = (f16)val;
                        }
                    }
                } else {
                    ((float*)out)[(size_t)m * C_ + n] = val;
                }
            }
}

// ---------------------------------------------------------------------------
// MFMA flash attention (f16 in, fp32 accum; verified round 4). Output f16.
// Barriers hardened with DRAIN_SYNC (same WAR-race class as the GEMM).
// ---------------------------------------------------------------------------
__global__ __launch_bounds__(256) void attn_mfma(const f16* __restrict__ Qf,
                                                 const f16* __restrict__ Kf,
                                                 const f16* __restrict__ Vf,
                                                 f16* __restrict__ AO) {
    __shared__ __align__(16) f16 Kh[64 * 64];     // [key][d] swizzled
    __shared__ __align__(16) f16 Vt[64 * 64];     // [d][j]  swizzled
    __shared__ __align__(16) f16 Pl[4][16 * 64];  // per-wave [qr][j] swizzled

    const int tid = threadIdx.x;
    const int lane = tid & 63;
    const int w = tid >> 6;
    const int g = lane >> 4;
    const int c = lane & 15;

    const int bh = blockIdx.x & 31;
    const int qt = blockIdx.x >> 5;

    const f16* Qp = Qf + ((size_t)(bh * T_ + qt * 64 + w * 16 + c)) * 64 + g * 8;
    const f16x8 qa0 = *(const f16x8*)(Qp);
    const f16x8 qa1 = *(const f16x8*)(Qp + 32);

    f32x4 o[4];
    float mrow[4], lsum[4];
#pragma unroll
    for (int i = 0; i < 4; ++i) {
        f32x4 z = {0.f, 0.f, 0.f, 0.f};
        o[i] = z;
        mrow[i] = -INFINITY;
        lsum[i] = 0.f;
    }

    const f16* Ktile = Kf + (size_t)bh * 32 * 4096;
    const f16* Vtile = Vf + (size_t)bh * 32 * 4096;

    const int soff0 = (w * 128 + lane) * 8;
    const int soff1 = (w * 128 + 64 + lane) * 8;

    uint4 kr0 = *(const uint4*)(Ktile + soff0);
    uint4 kr1 = *(const uint4*)(Ktile + soff1);
    uint4 vr0 = *(const uint4*)(Vtile + soff0);
    uint4 vr1 = *(const uint4*)(Vtile + soff1);

    f16* const Pw = Pl[w];

    for (int kt = 0; kt < 32; ++kt) {
        DRAIN_SYNC();   // all reads of previous tile complete before overwrite
        *(uint4*)(Kh + soff0) = kr0;
        *(uint4*)(Kh + soff1) = kr1;
        *(uint4*)(Vt + soff0) = vr0;
        *(uint4*)(Vt + soff1) = vr1;
        DRAIN_SYNC();   // staging writes landed before any wave reads

        if (kt < 31) {
            const f16* Kn = Ktile + (size_t)(kt + 1) * 4096;
            const f16* Vn = Vtile + (size_t)(kt + 1) * 4096;
            kr0 = *(const uint4*)(Kn + soff0);
            kr1 = *(const uint4*)(Kn + soff1);
            vr0 = *(const uint4*)(Vn + soff0);
            vr1 = *(const uint4*)(Vn + soff1);
        }

        f32x4 s[4];
#pragma unroll
        for (int jt = 0; jt < 4; ++jt) {
            f32x4 z = {0.f, 0.f, 0.f, 0.f};
            s[jt] = z;
        }
#pragma unroll
        for (int ks = 0; ks < 2; ++ks) {
            const f16x8 qa = ks ? qa1 : qa0;
#pragma unroll
            for (int jt = 0; jt < 4; ++jt) {
                const int row = jt * 16 + c;
                const f16x8 kb = *(const f16x8*)(Kh + row * 64 + (((ks * 4 + g) ^ (row & 7)) * 8));
                s[jt] = __builtin_amdgcn_mfma_f32_16x16x32_f16(qa, kb, s[jt], 0, 0, 0);
            }
        }

        float al[4];
#pragma unroll
        for (int r = 0; r < 4; ++r) {
            float mx = fmaxf(fmaxf(s[0][r], s[1][r]), fmaxf(s[2][r], s[3][r]));
            mx = fmaxf(mx, __shfl_xor(mx, 1));
            mx = fmaxf(mx, __shfl_xor(mx, 2));
            mx = fmaxf(mx, __shfl_xor(mx, 4));
            mx = fmaxf(mx, __shfl_xor(mx, 8));
            const float mn = fmaxf(mrow[r], mx);
            al[r] = __expf(mrow[r] - mn);
            mrow[r] = mn;
            float ps = 0.f;
#pragma unroll
            for (int jt = 0; jt < 4; ++jt) {
                const float p = __expf(s[jt][r] - mn);
                s[jt][r] = p;
                ps += p;
            }
            lsum[r] = lsum[r] * al[r] + ps;
        }

#pragma unroll
        for (int jt = 0; jt < 4; ++jt)
#pragma unroll
            for (int r = 0; r < 4; ++r) {
                const int row = g * 4 + r;
                const int ch = (jt * 2 + (c >> 3)) ^ (row & 7);
                Pw[row * 64 + ch * 8 + (c & 7)] = (f16)s[jt][r];
            }
        asm volatile("s_waitcnt lgkmcnt(0)" ::: "memory");  // wave-internal P visible
        __builtin_amdgcn_sched_barrier(0);                  // rule #18: pin against hoist/sink

#pragma unroll
        for (int dt = 0; dt < 4; ++dt)
#pragma unroll
            for (int r = 0; r < 4; ++r) o[dt][r] *= al[r];

#pragma unroll
        for (int ks = 0; ks < 2; ++ks) {
            const f16x8 pa = *(const f16x8*)(Pw + c * 64 + (((ks * 4 + g) ^ (c & 7)) * 8));
#pragma unroll
            for (int dt = 0; dt < 4; ++dt) {
                const int row = dt * 16 + c;
                const f16x8 vb = *(const f16x8*)(Vt + row * 64 + (((ks * 4 + g) ^ (row & 7)) * 8));
                o[dt] = __builtin_amdgcn_mfma_f32_16x16x32_f16(pa, vb, o[dt], 0, 0, 0);
            }
        }
    }

#pragma unroll
    for (int r = 0; r < 4; ++r) {
        float v = lsum[r];
        v += __shfl_xor(v, 1);
        v += __shfl_xor(v, 2);
        v += __shfl_xor(v, 4);
        v += __shfl_xor(v, 8);
        lsum[r] = 1.f / v;
    }
    const int b = bh >> 4, h = bh & 15;
#pragma unroll
    for (int dt = 0; dt < 4; ++dt)
#pragma unroll
        for (int r = 0; r < 4; ++r) {
            const int row = qt * 64 + w * 16 + g * 4 + r;
            AO[((size_t)(b * T_ + row)) * C_ + h * 64 + dt * 16 + c] = (f16)(o[dt][r] * lsum[r]);
        }
}

extern "C" void kernel_launch(void* const* d_in, const int* in_sizes, int n_in,
                              void* d_out, int out_size, void* d_ws, size_t ws_size,
                              hipStream_t stream) {
    const float* x     = (const float*)d_in[0];
    const float* W_qkv = (const float*)d_in[1];
    const float* b_qkv = (const float*)d_in[2];
    const float* W_o   = (const float*)d_in[3];
    const float* b_o   = (const float*)d_in[4];

    f16* ws16 = (f16*)d_ws;
    f16* xf  = ws16;                      // 4M f16: x cast
    f16* wqf = xf + 4194304;              // 3M f16: W_qkv cast
    f16* wof = wqf + 3145728;             // 1M f16: W_o cast
    f16* Qf  = wof + 1048576;             // 3 x 4M f16: Q | K(swz) | V^T(swz)
    f16* AOf = Qf + (size_t)3 * QKVSZ;    // 4M f16: attention out [M][1024]

    // 0) cast x, W_qkv, W_o to f16
    cvt_kernel<<<dim3(4096), dim3(256), 0, stream>>>(x, W_qkv, W_o, xf, wqf, wof);

    // 1) QKV projection (f16 MFMA, fp32 accum) -> Q/K/V^T attention layouts
    gemm_f16<0><<<dim3(32 * 24), dim3(256), 0, stream>>>(xf, wqf, b_qkv, (void*)Qf, 32);

    // 2) MFMA flash attention
    attn_mfma<<<dim3(32 * 32), dim3(256), 0, stream>>>(Qf, Qf + QKVSZ, Qf + 2 * QKVSZ, AOf);

    // 3) output projection (f16 MFMA, fp32 accum) -> fp32 out
    gemm_f16<1><<<dim3(32 * 8), dim3(256), 0, stream>>>(AOf, wof, b_o, d_out, 32);
}

// Round 10
// 218.574 us; speedup vs baseline: 8.1646x; 1.1032x over previous
//
#include <hip/hip_runtime.h>
#include <math.h>

#define B_ 2
#define T_ 2048
#define C_ 1024
#define H_ 16
#define M_ (B_*T_)            // 4096
#define QKVSZ (B_*H_*T_*64)   // 4194304 elements per tensor

typedef _Float16 f16;
typedef _Float16 f16x4 __attribute__((ext_vector_type(4)));
typedef _Float16 f16x8 __attribute__((ext_vector_type(8)));
typedef float f32x4 __attribute__((ext_vector_type(4)));

// async global->LDS, 16B per lane; LDS dest is wave-uniform base + lane*16
#define GLL16(g, l) __builtin_amdgcn_global_load_lds(                     \
    (const __attribute__((address_space(1))) void*)(g),                   \
    (__attribute__((address_space(3))) void*)(l), 16, 0, 0)

// Full drain barrier (gemm: global_load_lds needs vmcnt at the barrier).
#define DRAIN_SYNC() do {                                                 \
    asm volatile("s_waitcnt vmcnt(0) lgkmcnt(0)" ::: "memory");           \
    __builtin_amdgcn_sched_barrier(0);                                    \
    __syncthreads();                                                      \
} while (0)

// LDS-only drain barrier (attn: staging is reg->ds_write, so only lgkmcnt
// gates LDS visibility; global prefetch loads stay in flight across it).
#define LGKM_BAR() do {                                                   \
    asm volatile("s_waitcnt lgkmcnt(0)" ::: "memory");                    \
    __builtin_amdgcn_sched_barrier(0);                                    \
    __builtin_amdgcn_s_barrier();                                         \
    __builtin_amdgcn_sched_barrier(0);                                    \
} while (0)

// ---------------------------------------------------------------------------
// fp32 -> f16 cast prepass: x (4M), W_qkv (3M), W_o (1M). 2048 elems/block.
// ---------------------------------------------------------------------------
__global__ __launch_bounds__(256) void cvt_kernel(const float* __restrict__ x,
                                                  const float* __restrict__ wq,
                                                  const float* __restrict__ wo,
                                                  f16* __restrict__ xf,
                                                  f16* __restrict__ wqf,
                                                  f16* __restrict__ wof) {
    const int b = blockIdx.x;
    const float* src;
    f16* dst;
    size_t off;
    if (b < 2048)      { src = x;  dst = xf;  off = (size_t)b * 2048; }
    else if (b < 3584) { src = wq; dst = wqf; off = (size_t)(b - 2048) * 2048; }
    else               { src = wo; dst = wof; off = (size_t)(b - 3584) * 2048; }
    const size_t e = off + (size_t)threadIdx.x * 8;
    const float4 v0 = *(const float4*)(src + e);
    const float4 v1 = *(const float4*)(src + e + 4);
    f16x8 r = {(f16)v0.x, (f16)v0.y, (f16)v0.z, (f16)v0.w,
               (f16)v1.x, (f16)v1.y, (f16)v1.z, (f16)v1.w};
    *(f16x8*)(dst + e) = r;
}

// ---------------------------------------------------------------------------
// f16 MFMA GEMM (verified round 9, unchanged). BM=BN=128, BK=32, 4 waves.
// ---------------------------------------------------------------------------
template <int WRITE_MODE>
__global__ __launch_bounds__(256) void gemm_f16(const f16* __restrict__ Af,
                                                const f16* __restrict__ Bf,
                                                const float* __restrict__ bias,
                                                void* __restrict__ out,
                                                int nbm) {
    __shared__ __align__(16) f16 At[2][128 * 32];
    __shared__ __align__(16) f16 Bt[2][128 * 32];

    const int tid = threadIdx.x;
    const int l = tid & 63;
    const int w = tid >> 6;
    const int c = l & 15, g = l >> 4;
    const int wr = w >> 1, wc = w & 1;
    const int bm = blockIdx.x % nbm, bn = blockIdx.x / nbm;

    const f16* Ag = Af + (size_t)(bm * 128 + w * 32 + (l >> 2)) * 1024 + (l & 3) * 8;
    const f16* Bg = Bf + (size_t)(bn * 128 + w * 32 + (l >> 2)) * 1024 + (l & 3) * 8;

    f32x4 acc[4][4];
#pragma unroll
    for (int mt = 0; mt < 4; ++mt)
#pragma unroll
        for (int nt = 0; nt < 4; ++nt) {
            f32x4 z = {0.f, 0.f, 0.f, 0.f};
            acc[mt][nt] = z;
        }

    GLL16(Ag,         &At[0][w * 1024]);
    GLL16(Ag + 16384, &At[0][w * 1024 + 512]);
    GLL16(Bg,         &Bt[0][w * 1024]);
    GLL16(Bg + 16384, &Bt[0][w * 1024 + 512]);
    DRAIN_SYNC();

    int cur = 0;
    for (int ks = 0; ks < 32; ++ks) {
        if (ks < 31) {
            const int k0 = (ks + 1) * 32;
            GLL16(Ag + k0,         &At[cur ^ 1][w * 1024]);
            GLL16(Ag + k0 + 16384, &At[cur ^ 1][w * 1024 + 512]);
            GLL16(Bg + k0,         &Bt[cur ^ 1][w * 1024]);
            GLL16(Bg + k0 + 16384, &Bt[cur ^ 1][w * 1024 + 512]);
        }
        const f16* Acur = At[cur];
        const f16* Bcur = Bt[cur];
        f16x8 af[4];
#pragma unroll
        for (int mt = 0; mt < 4; ++mt)
            af[mt] = *(const f16x8*)(Acur + (wr * 64 + mt * 16 + c) * 32 + g * 8);
#pragma unroll
        for (int nt = 0; nt < 4; ++nt) {
            const f16x8 bfr = *(const f16x8*)(Bcur + (wc * 64 + nt * 16 + c) * 32 + g * 8);
#pragma unroll
            for (int mt = 0; mt < 4; ++mt)
                acc[mt][nt] = __builtin_amdgcn_mfma_f32_16x16x32_f16(af[mt], bfr, acc[mt][nt], 0, 0, 0);
        }
        DRAIN_SYNC();
        cur ^= 1;
    }

#pragma unroll
    for (int mt = 0; mt < 4; ++mt)
#pragma unroll
        for (int nt = 0; nt < 4; ++nt)
#pragma unroll
            for (int r = 0; r < 4; ++r) {
                const int m = bm * 128 + wr * 64 + mt * 16 + g * 4 + r;
                const int n = bn * 128 + wc * 64 + nt * 16 + c;
                const float val = acc[mt][nt][r] + bias[n];
                if (WRITE_MODE == 0) {
                    const int s = n >> 10, h = (n >> 6) & 15, d = n & 63;
                    const int b = m >> 11, t = m & 2047;
                    const int bh = b * H_ + h;
                    f16* base = (f16*)out;
                    if (s == 0) {
                        base[((size_t)(bh * T_ + t)) * 64 + d] = (f16)(val * 0.125f);
                    } else {
                        const int tile = t >> 6, row = t & 63;
                        if (s == 1) {
                            const int ch = (d >> 3) ^ (row & 7);
                            base[(size_t)QKVSZ +
                                 ((size_t)((bh * 32 + tile) * 64 + row)) * 64 + ch * 8 + (d & 7)] = (f16)val;
                        } else {
                            const int cj = (row >> 3) ^ (d & 7);
                            base[(size_t)(2 * QKVSZ) +
                                 ((size_t)((bh * 32 + tile) * 64 + d)) * 64 + cj * 8 + (row & 7)] = (f16)val;
                        }
                    }
                } else {
                    ((float*)out)[(size_t)m * C_ + n] = val;
                }
            }
}

// ---------------------------------------------------------------------------
// MFMA flash attention v2: swapped QK^T (S^T in regs -> q-row is lane-local),
// in-lane softmax (2 shfl instead of 16), packed b64 P-transpose, K/V LDS
// double-buffered (one lgkm-only barrier per tile), reg prefetch 2 tiles ahead.
// ---------------------------------------------------------------------------
__global__ __launch_bounds__(256) void attn_mfma(const f16* __restrict__ Qf,
                                                 const f16* __restrict__ Kf,
                                                 const f16* __restrict__ Vf,
                                                 f16* __restrict__ AO) {
    __shared__ __align__(16) f16 Kh[2][64 * 64];  // [buf][key][d] swizzled
    __shared__ __align__(16) f16 Vt[2][64 * 64];  // [buf][d][j]  swizzled
    __shared__ __align__(16) f16 Pl[4][16 * 64];  // per-wave [q=c][key] swizzled

    const int tid = threadIdx.x;
    const int lane = tid & 63;
    const int w = tid >> 6;
    const int g = lane >> 4;
    const int c = lane & 15;

    const int bh = blockIdx.x & 31;
    const int qt = blockIdx.x >> 5;

    // Q fragment (B-operand now): row j = c -> q-row w*16+c, k-elems g*8 (+32)
    const f16* Qp = Qf + ((size_t)(bh * T_ + qt * 64 + w * 16 + c)) * 64 + g * 8;
    const f16x8 qa0 = *(const f16x8*)(Qp);
    const f16x8 qa1 = *(const f16x8*)(Qp + 32);

    f32x4 o[4];
#pragma unroll
    for (int i = 0; i < 4; ++i) {
        f32x4 z = {0.f, 0.f, 0.f, 0.f};
        o[i] = z;
    }
    float mrow = -INFINITY, lsum = 0.f;  // one q-row (q = c) per lane

    const f16* Ktile = Kf + (size_t)bh * 32 * 4096;
    const f16* Vtile = Vf + (size_t)bh * 32 * 4096;

    const int soff0 = (w * 128 + lane) * 8;
    const int soff1 = (w * 128 + 64 + lane) * 8;

    // prologue: tile 0 -> LDS buf 0; tile 1 -> regs
    {
        uint4 a = *(const uint4*)(Ktile + soff0);
        uint4 b = *(const uint4*)(Ktile + soff1);
        uint4 cc = *(const uint4*)(Vtile + soff0);
        uint4 d = *(const uint4*)(Vtile + soff1);
        *(uint4*)(&Kh[0][soff0]) = a;
        *(uint4*)(&Kh[0][soff1]) = b;
        *(uint4*)(&Vt[0][soff0]) = cc;
        *(uint4*)(&Vt[0][soff1]) = d;
    }
    uint4 kr0 = *(const uint4*)(Ktile + 4096 + soff0);
    uint4 kr1 = *(const uint4*)(Ktile + 4096 + soff1);
    uint4 vr0 = *(const uint4*)(Vtile + 4096 + soff0);
    uint4 vr1 = *(const uint4*)(Vtile + 4096 + soff1);
    LGKM_BAR();

    f16* const Pw = Pl[w];

    for (int kt = 0; kt < 32; ++kt) {
        const int cb = kt & 1;
        const f16* Kc = Kh[cb];
        const f16* Vc = Vt[cb];

        // ---- QK^T swapped: S^T. A=K (row=key), B=Q (row=q). 8 MFMAs.
        // D: col=c=q-local, row=g*4+r=key-local (per 16-key jt tile).
        f32x4 s[4];
#pragma unroll
        for (int jt = 0; jt < 4; ++jt) {
            f32x4 z = {0.f, 0.f, 0.f, 0.f};
            s[jt] = z;
        }
#pragma unroll
        for (int ks = 0; ks < 2; ++ks) {
            const f16x8 qa = ks ? qa1 : qa0;
#pragma unroll
            for (int jt = 0; jt < 4; ++jt) {
                const int row = jt * 16 + c;  // key index
                const f16x8 kb = *(const f16x8*)(Kc + row * 64 + (((ks * 4 + g) ^ (row & 7)) * 8));
                s[jt] = __builtin_amdgcn_mfma_f32_16x16x32_f16(kb, qa, s[jt], 0, 0, 0);
            }
        }

        // ---- stage next tile (regs -> other buffer); overlaps softmax VALU
        if (kt < 31) {
            f16* Kn = Kh[cb ^ 1];
            f16* Vn = Vt[cb ^ 1];
            *(uint4*)(Kn + soff0) = kr0;
            *(uint4*)(Kn + soff1) = kr1;
            *(uint4*)(Vn + soff0) = vr0;
            *(uint4*)(Vn + soff1) = vr1;
        }
        // ---- prefetch tile kt+2 into regs (L2-hit latency hides under compute)
        if (kt < 30) {
            const f16* Kg2 = Ktile + (size_t)(kt + 2) * 4096;
            const f16* Vg2 = Vtile + (size_t)(kt + 2) * 4096;
            kr0 = *(const uint4*)(Kg2 + soff0);
            kr1 = *(const uint4*)(Kg2 + soff1);
            vr0 = *(const uint4*)(Vg2 + soff0);
            vr1 = *(const uint4*)(Vg2 + soff1);
        }

        // ---- softmax: lane owns q=c; its 16 scores cover keys {16jt+4g+r}.
        float mx = s[0][0];
#pragma unroll
        for (int jt = 0; jt < 4; ++jt)
#pragma unroll
            for (int r = 0; r < 4; ++r) mx = fmaxf(mx, s[jt][r]);
        mx = fmaxf(mx, __shfl_xor(mx, 16));
        mx = fmaxf(mx, __shfl_xor(mx, 32));
        const float mn = fmaxf(mrow, mx);
        const float alpha = __expf(mrow - mn);
        mrow = mn;
        float ps = 0.f;
#pragma unroll
        for (int jt = 0; jt < 4; ++jt)
#pragma unroll
            for (int r = 0; r < 4; ++r) {
                const float p = __expf(s[jt][r] - mn);
                s[jt][r] = p;
                ps += p;
            }
        lsum = lsum * alpha + ps;  // lane-partial (keys of this g); reduced at end

        // ---- P -> LDS: elem offset == key, chunk-XOR swizzle, b64 writes.
        // lane (c,g), jt writes keys 16jt+4g..+3 at chunk (2jt+(g>>1))^(c&7), half g&1.
#pragma unroll
        for (int jt = 0; jt < 4; ++jt) {
            f16x4 v = {(f16)s[jt][0], (f16)s[jt][1], (f16)s[jt][2], (f16)s[jt][3]};
            *(f16x4*)(Pw + c * 64 + (((2 * jt + (g >> 1)) ^ (c & 7)) * 8) + 4 * (g & 1)) = v;
        }
        asm volatile("s_waitcnt lgkmcnt(0)" ::: "memory");  // wave-internal P visible
        __builtin_amdgcn_sched_barrier(0);                  // rule #18 fence

        // ---- rescale O: O rows are q=g*4+r; fetch their alphas (lanes 0-15)
        float alr[4];
#pragma unroll
        for (int r = 0; r < 4; ++r) alr[r] = __shfl(alpha, g * 4 + r);
#pragma unroll
        for (int dt = 0; dt < 4; ++dt)
#pragma unroll
            for (int r = 0; r < 4; ++r) o[dt][r] *= alr[r];

        // ---- PV: A=P (row=q), B=V^T (row=d). 8 MFMAs.
#pragma unroll
        for (int ks = 0; ks < 2; ++ks) {
            const f16x8 pa = *(const f16x8*)(Pw + c * 64 + (((ks * 4 + g) ^ (c & 7)) * 8));
#pragma unroll
            for (int dt = 0; dt < 4; ++dt) {
                const int row = dt * 16 + c;  // d index
                const f16x8 vb = *(const f16x8*)(Vc + row * 64 + (((ks * 4 + g) ^ (row & 7)) * 8));
                o[dt] = __builtin_amdgcn_mfma_f32_16x16x32_f16(pa, vb, o[dt], 0, 0, 0);
            }
        }

        LGKM_BAR();  // my LDS reads done + staging writes visible; vmem stays in flight
    }

    // ---- final: full row-sum = reduce lane-partials across the 4 g-lanes
    float L = lsum;
    L += __shfl_xor(L, 16);
    L += __shfl_xor(L, 32);
    const float inv = 1.f / L;
    float invr[4];
#pragma unroll
    for (int r = 0; r < 4; ++r) invr[r] = __shfl(inv, g * 4 + r);

    const int b = bh >> 4, h = bh & 15;
#pragma unroll
    for (int dt = 0; dt < 4; ++dt)
#pragma unroll
        for (int r = 0; r < 4; ++r) {
            const int row = qt * 64 + w * 16 + g * 4 + r;
            AO[((size_t)(b * T_ + row)) * C_ + h * 64 + dt * 16 + c] = (f16)(o[dt][r] * invr[r]);
        }
}

extern "C" void kernel_launch(void* const* d_in, const int* in_sizes, int n_in,
                              void* d_out, int out_size, void* d_ws, size_t ws_size,
                              hipStream_t stream) {
    const float* x     = (const float*)d_in[0];
    const float* W_qkv = (const float*)d_in[1];
    const float* b_qkv = (const float*)d_in[2];
    const float* W_o   = (const float*)d_in[3];
    const float* b_o   = (const float*)d_in[4];

    f16* ws16 = (f16*)d_ws;
    f16* xf  = ws16;                      // 4M f16: x cast
    f16* wqf = xf + 4194304;              // 3M f16: W_qkv cast
    f16* wof = wqf + 3145728;             // 1M f16: W_o cast
    f16* Qf  = wof + 1048576;             // 3 x 4M f16: Q | K(swz) | V^T(swz)
    f16* AOf = Qf + (size_t)3 * QKVSZ;    // 4M f16: attention out [M][1024]

    // 0) cast x, W_qkv, W_o to f16
    cvt_kernel<<<dim3(4096), dim3(256), 0, stream>>>(x, W_qkv, W_o, xf, wqf, wof);

    // 1) QKV projection (f16 MFMA, fp32 accum) -> Q/K/V^T attention layouts
    gemm_f16<0><<<dim3(32 * 24), dim3(256), 0, stream>>>(xf, wqf, b_qkv, (void*)Qf, 32);

    // 2) MFMA flash attention
    attn_mfma<<<dim3(32 * 32), dim3(256), 0, stream>>>(Qf, Qf + QKVSZ, Qf + 2 * QKVSZ, AOf);

    // 3) output projection (f16 MFMA, fp32 accum) -> fp32 out
    gemm_f16<1><<<dim3(32 * 8), dim3(256), 0, stream>>>(AOf, wof, b_o, d_out, 32);
}

// Round 12
// 210.257 us; speedup vs baseline: 8.4876x; 1.0396x over previous
//
#include <hip/hip_runtime.h>
#include <math.h>

#define B_ 2
#define T_ 2048
#define C_ 1024
#define H_ 16
#define M_ (B_*T_)            // 4096
#define QKVSZ (B_*H_*T_*64)   // 4194304 elements per tensor

typedef _Float16 f16;
typedef _Float16 f16x4 __attribute__((ext_vector_type(4)));
typedef _Float16 f16x8 __attribute__((ext_vector_type(8)));
typedef float f32x4 __attribute__((ext_vector_type(4)));

// async global->LDS, 16B per lane; LDS dest is wave-uniform base + lane*16
#define GLL16(g, l) __builtin_amdgcn_global_load_lds(                     \
    (const __attribute__((address_space(1))) void*)(g),                   \
    (__attribute__((address_space(3))) void*)(l), 16, 0, 0)

// LDS-drain barrier: lgkmcnt(0) pinned before s_barrier (rule #18: compiler
// sinks register-only MFMA past asm waits; sched_barrier(0) fences it).
// vmcnt deliberately NOT drained here (T4 counted-vmcnt: loads stay in
// flight across the barrier).
#define LGKM_BAR() do {                                                   \
    asm volatile("s_waitcnt lgkmcnt(0)" ::: "memory");                    \
    __builtin_amdgcn_sched_barrier(0);                                    \
    __builtin_amdgcn_s_barrier();                                         \
    __builtin_amdgcn_sched_barrier(0);                                    \
} while (0)

// ---------------------------------------------------------------------------
// fp32 -> f16 cast prepass: x (4M), W_qkv (3M), W_o (1M). 2048 elems/block.
// ---------------------------------------------------------------------------
__global__ __launch_bounds__(256) void cvt_kernel(const float* __restrict__ x,
                                                  const float* __restrict__ wq,
                                                  const float* __restrict__ wo,
                                                  f16* __restrict__ xf,
                                                  f16* __restrict__ wqf,
                                                  f16* __restrict__ wof) {
    const int b = blockIdx.x;
    const float* src;
    f16* dst;
    size_t off;
    if (b < 2048)      { src = x;  dst = xf;  off = (size_t)b * 2048; }
    else if (b < 3584) { src = wq; dst = wqf; off = (size_t)(b - 2048) * 2048; }
    else               { src = wo; dst = wof; off = (size_t)(b - 3584) * 2048; }
    const size_t e = off + (size_t)threadIdx.x * 8;
    const float4 v0 = *(const float4*)(src + e);
    const float4 v1 = *(const float4*)(src + e + 4);
    f16x8 r = {(f16)v0.x, (f16)v0.y, (f16)v0.z, (f16)v0.w,
               (f16)v1.x, (f16)v1.y, (f16)v1.z, (f16)v1.w};
    *(f16x8*)(dst + e) = r;
}

// ---------------------------------------------------------------------------
// f16 MFMA GEMM, T4 counted-vmcnt pipeline: BM=BN=128, BK=32, 4 waves (2x2),
// TRIPLE-buffered LDS (48KB, 3 blocks/CU), prefetch 2 K-tiles ahead via
// global_load_lds. Per K-step: {lgkm(0); s_barrier; STAGE(t+2); vmcnt(8);
// ds_read + 16 MFMA}. vmcnt(8) leaves tiles t+1,t+2 (4 loads each) in
// flight — replaces the full vmcnt(0) drain (m233: ~72% of 2-phase time).
// WAR-safe: slot (t+2)%3's readers ran at iter t-1, drained at this barrier.
// ---------------------------------------------------------------------------
template <int WRITE_MODE>
__global__ __launch_bounds__(256) void gemm_f16(const f16* __restrict__ Af,
                                                const f16* __restrict__ Bf,
                                                const float* __restrict__ bias,
                                                void* __restrict__ out,
                                                int nbm) {
    __shared__ __align__(16) f16 At[3][128 * 32];
    __shared__ __align__(16) f16 Bt[3][128 * 32];

    const int tid = threadIdx.x;
    const int l = tid & 63;
    const int w = tid >> 6;
    const int c = l & 15, g = l >> 4;
    const int wr = w >> 1, wc = w & 1;
    const int bm = blockIdx.x % nbm, bn = blockIdx.x / nbm;

    // staging: wave w covers tile rows [w*32, w*32+32); lane l -> row w*32+(l>>2), k (l&3)*8
    const f16* Ag = Af + (size_t)(bm * 128 + w * 32 + (l >> 2)) * 1024 + (l & 3) * 8;
    const f16* Bg = Bf + (size_t)(bn * 128 + w * 32 + (l >> 2)) * 1024 + (l & 3) * 8;

    f32x4 acc[4][4];
#pragma unroll
    for (int mt = 0; mt < 4; ++mt)
#pragma unroll
        for (int nt = 0; nt < 4; ++nt) {
            f32x4 z = {0.f, 0.f, 0.f, 0.f};
            acc[mt][nt] = z;
        }

#define STAGE(KT, SLOT) do {                                              \
        const int k0_ = (KT) * 32;                                        \
        GLL16(Ag + k0_,         &At[SLOT][w * 1024]);                     \
        GLL16(Ag + k0_ + 16384, &At[SLOT][w * 1024 + 512]);               \
        GLL16(Bg + k0_,         &Bt[SLOT][w * 1024]);                     \
        GLL16(Bg + k0_ + 16384, &Bt[SLOT][w * 1024 + 512]);               \
    } while (0)

#define COMPUTE(SLOT) do {                                                \
        const f16* Acur = At[SLOT];                                       \
        const f16* Bcur = Bt[SLOT];                                       \
        f16x8 af[4];                                                      \
        _Pragma("unroll")                                                 \
        for (int mt = 0; mt < 4; ++mt)                                    \
            af[mt] = *(const f16x8*)(Acur + (wr * 64 + mt * 16 + c) * 32 + g * 8); \
        _Pragma("unroll")                                                 \
        for (int nt = 0; nt < 4; ++nt) {                                  \
            const f16x8 bfr = *(const f16x8*)(Bcur + (wc * 64 + nt * 16 + c) * 32 + g * 8); \
            _Pragma("unroll")                                             \
            for (int mt = 0; mt < 4; ++mt)                                \
                acc[mt][nt] = __builtin_amdgcn_mfma_f32_16x16x32_f16(af[mt], bfr, acc[mt][nt], 0, 0, 0); \
        }                                                                 \
    } while (0)

#define KSTEP(KT, SLOT, NSLOT) do {                                       \
        LGKM_BAR();                                                       \
        STAGE((KT) + 2, NSLOT);                                           \
        asm volatile("s_waitcnt vmcnt(8)" ::: "memory");                  \
        __builtin_amdgcn_sched_barrier(0);                                \
        COMPUTE(SLOT);                                                    \
    } while (0)

    // prologue: tiles 0,1 in flight
    STAGE(0, 0);
    STAGE(1, 1);

    // main: t = 0..29, slots cycle 0,1,2; stage t+2 into slot (t+2)%3
    for (int tb = 0; tb < 30; tb += 3) {
        KSTEP(tb + 0, 0, 2);
        KSTEP(tb + 1, 1, 0);
        KSTEP(tb + 2, 2, 1);
    }
    // tail: t=30 (slot 0; only t31's 4 loads outstanding), t=31 (slot 1)
    LGKM_BAR();
    asm volatile("s_waitcnt vmcnt(4)" ::: "memory");
    __builtin_amdgcn_sched_barrier(0);
    COMPUTE(0);
    LGKM_BAR();
    asm volatile("s_waitcnt vmcnt(0)" ::: "memory");
    __builtin_amdgcn_sched_barrier(0);
    COMPUTE(1);

#undef KSTEP
#undef COMPUTE
#undef STAGE

    // epilogue: C/D layout col=lane&15, row=(lane>>4)*4+reg
#pragma unroll
    for (int mt = 0; mt < 4; ++mt)
#pragma unroll
        for (int nt = 0; nt < 4; ++nt)
#pragma unroll
            for (int r = 0; r < 4; ++r) {
                const int m = bm * 128 + wr * 64 + mt * 16 + g * 4 + r;
                const int n = bn * 128 + wc * 64 + nt * 16 + c;
                const float val = acc[mt][nt][r] + bias[n];
                if (WRITE_MODE == 0) {
                    const int s = n >> 10, h = (n >> 6) & 15, d = n & 63;
                    const int b = m >> 11, t = m & 2047;
                    const int bh = b * H_ + h;
                    f16* base = (f16*)out;
                    if (s == 0) {
                        base[((size_t)(bh * T_ + t)) * 64 + d] = (f16)(val * 0.125f);
                    } else {
                        const int tile = t >> 6, row = t & 63;
                        if (s == 1) {
                            const int ch = (d >> 3) ^ (row & 7);
                            base[(size_t)QKVSZ +
                                 ((size_t)((bh * 32 + tile) * 64 + row)) * 64 + ch * 8 + (d & 7)] = (f16)val;
                        } else {
                            const int cj = (row >> 3) ^ (d & 7);
                            base[(size_t)(2 * QKVSZ) +
                                 ((size_t)((bh * 32 + tile) * 64 + d)) * 64 + cj * 8 + (row & 7)] = (f16)val;
                        }
                    }
                } else {
                    ((float*)out)[(size_t)m * C_ + n] = val;
                }
            }
}

// ---------------------------------------------------------------------------
// MFMA flash attention v2 (verified round 10, unchanged): swapped QK^T,
// in-lane softmax, packed b64 P-transpose, K/V LDS double-buffer, one
// lgkm-only barrier per tile, reg prefetch 2 tiles ahead.
// ---------------------------------------------------------------------------
__global__ __launch_bounds__(256) void attn_mfma(const f16* __restrict__ Qf,
                                                 const f16* __restrict__ Kf,
                                                 const f16* __restrict__ Vf,
                                                 f16* __restrict__ AO) {
    __shared__ __align__(16) f16 Kh[2][64 * 64];  // [buf][key][d] swizzled
    __shared__ __align__(16) f16 Vt[2][64 * 64];  // [buf][d][j]  swizzled
    __shared__ __align__(16) f16 Pl[4][16 * 64];  // per-wave [q=c][key] swizzled

    const int tid = threadIdx.x;
    const int lane = tid & 63;
    const int w = tid >> 6;
    const int g = lane >> 4;
    const int c = lane & 15;

    const int bh = blockIdx.x & 31;
    const int qt = blockIdx.x >> 5;

    const f16* Qp = Qf + ((size_t)(bh * T_ + qt * 64 + w * 16 + c)) * 64 + g * 8;
    const f16x8 qa0 = *(const f16x8*)(Qp);
    const f16x8 qa1 = *(const f16x8*)(Qp + 32);

    f32x4 o[4];
#pragma unroll
    for (int i = 0; i < 4; ++i) {
        f32x4 z = {0.f, 0.f, 0.f, 0.f};
        o[i] = z;
    }
    float mrow = -INFINITY, lsum = 0.f;  // one q-row (q = c) per lane

    const f16* Ktile = Kf + (size_t)bh * 32 * 4096;
    const f16* Vtile = Vf + (size_t)bh * 32 * 4096;

    const int soff0 = (w * 128 + lane) * 8;
    const int soff1 = (w * 128 + 64 + lane) * 8;

    {
        uint4 a = *(const uint4*)(Ktile + soff0);
        uint4 b = *(const uint4*)(Ktile + soff1);
        uint4 cc = *(const uint4*)(Vtile + soff0);
        uint4 d = *(const uint4*)(Vtile + soff1);
        *(uint4*)(&Kh[0][soff0]) = a;
        *(uint4*)(&Kh[0][soff1]) = b;
        *(uint4*)(&Vt[0][soff0]) = cc;
        *(uint4*)(&Vt[0][soff1]) = d;
    }
    uint4 kr0 = *(const uint4*)(Ktile + 4096 + soff0);
    uint4 kr1 = *(const uint4*)(Ktile + 4096 + soff1);
    uint4 vr0 = *(const uint4*)(Vtile + 4096 + soff0);
    uint4 vr1 = *(const uint4*)(Vtile + 4096 + soff1);
    LGKM_BAR();

    f16* const Pw = Pl[w];

    for (int kt = 0; kt < 32; ++kt) {
        const int cb = kt & 1;
        const f16* Kc = Kh[cb];
        const f16* Vc = Vt[cb];

        // ---- QK^T swapped: S^T. A=K (row=key), B=Q (row=q). 8 MFMAs.
        f32x4 s[4];
#pragma unroll
        for (int jt = 0; jt < 4; ++jt) {
            f32x4 z = {0.f, 0.f, 0.f, 0.f};
            s[jt] = z;
        }
#pragma unroll
        for (int ks = 0; ks < 2; ++ks) {
            const f16x8 qa = ks ? qa1 : qa0;
#pragma unroll
            for (int jt = 0; jt < 4; ++jt) {
                const int row = jt * 16 + c;  // key index
                const f16x8 kb = *(const f16x8*)(Kc + row * 64 + (((ks * 4 + g) ^ (row & 7)) * 8));
                s[jt] = __builtin_amdgcn_mfma_f32_16x16x32_f16(kb, qa, s[jt], 0, 0, 0);
            }
        }

        // ---- stage next tile (regs -> other buffer); overlaps softmax VALU
        if (kt < 31) {
            f16* Kn = Kh[cb ^ 1];
            f16* Vn = Vt[cb ^ 1];
            *(uint4*)(Kn + soff0) = kr0;
            *(uint4*)(Kn + soff1) = kr1;
            *(uint4*)(Vn + soff0) = vr0;
            *(uint4*)(Vn + soff1) = vr1;
        }
        // ---- prefetch tile kt+2 into regs
        if (kt < 30) {
            const f16* Kg2 = Ktile + (size_t)(kt + 2) * 4096;
            const f16* Vg2 = Vtile + (size_t)(kt + 2) * 4096;
            kr0 = *(const uint4*)(Kg2 + soff0);
            kr1 = *(const uint4*)(Kg2 + soff1);
            vr0 = *(const uint4*)(Vg2 + soff0);
            vr1 = *(const uint4*)(Vg2 + soff1);
        }

        // ---- softmax: lane owns q=c
        float mx = s[0][0];
#pragma unroll
        for (int jt = 0; jt < 4; ++jt)
#pragma unroll
            for (int r = 0; r < 4; ++r) mx = fmaxf(mx, s[jt][r]);
        mx = fmaxf(mx, __shfl_xor(mx, 16));
        mx = fmaxf(mx, __shfl_xor(mx, 32));
        const float mn = fmaxf(mrow, mx);
        const float alpha = __expf(mrow - mn);
        mrow = mn;
        float ps = 0.f;
#pragma unroll
        for (int jt = 0; jt < 4; ++jt)
#pragma unroll
            for (int r = 0; r < 4; ++r) {
                const float p = __expf(s[jt][r] - mn);
                s[jt][r] = p;
                ps += p;
            }
        lsum = lsum * alpha + ps;

        // ---- P -> LDS: packed b64 writes, chunk-XOR swizzle
#pragma unroll
        for (int jt = 0; jt < 4; ++jt) {
            f16x4 v = {(f16)s[jt][0], (f16)s[jt][1], (f16)s[jt][2], (f16)s[jt][3]};
            *(f16x4*)(Pw + c * 64 + (((2 * jt + (g >> 1)) ^ (c & 7)) * 8) + 4 * (g & 1)) = v;
        }
        asm volatile("s_waitcnt lgkmcnt(0)" ::: "memory");
        __builtin_amdgcn_sched_barrier(0);

        // ---- rescale O
        float alr[4];
#pragma unroll
        for (int r = 0; r < 4; ++r) alr[r] = __shfl(alpha, g * 4 + r);
#pragma unroll
        for (int dt = 0; dt < 4; ++dt)
#pragma unroll
            for (int r = 0; r < 4; ++r) o[dt][r] *= alr[r];

        // ---- PV: A=P (row=q), B=V^T (row=d). 8 MFMAs.
#pragma unroll
        for (int ks = 0; ks < 2; ++ks) {
            const f16x8 pa = *(const f16x8*)(Pw + c * 64 + (((ks * 4 + g) ^ (c & 7)) * 8));
#pragma unroll
            for (int dt = 0; dt < 4; ++dt) {
                const int row = dt * 16 + c;
                const f16x8 vb = *(const f16x8*)(Vc + row * 64 + (((ks * 4 + g) ^ (row & 7)) * 8));
                o[dt] = __builtin_amdgcn_mfma_f32_16x16x32_f16(pa, vb, o[dt], 0, 0, 0);
            }
        }

        LGKM_BAR();
    }

    float L = lsum;
    L += __shfl_xor(L, 16);
    L += __shfl_xor(L, 32);
    const float inv = 1.f / L;
    float invr[4];
#pragma unroll
    for (int r = 0; r < 4; ++r) invr[r] = __shfl(inv, g * 4 + r);

    const int b = bh >> 4, h = bh & 15;
#pragma unroll
    for (int dt = 0; dt < 4; ++dt)
#pragma unroll
        for (int r = 0; r < 4; ++r) {
            const int row = qt * 64 + w * 16 + g * 4 + r;
            AO[((size_t)(b * T_ + row)) * C_ + h * 64 + dt * 16 + c] = (f16)(o[dt][r] * invr[r]);
        }
}

extern "C" void kernel_launch(void* const* d_in, const int* in_sizes, int n_in,
                              void* d_out, int out_size, void* d_ws, size_t ws_size,
                              hipStream_t stream) {
    const float* x     = (const float*)d_in[0];
    const float* W_qkv = (const float*)d_in[1];
    const float* b_qkv = (const float*)d_in[2];
    const float* W_o   = (const float*)d_in[3];
    const float* b_o   = (const float*)d_in[4];

    f16* ws16 = (f16*)d_ws;
    f16* xf  = ws16;                      // 4M f16: x cast
    f16* wqf = xf + 4194304;              // 3M f16: W_qkv cast
    f16* wof = wqf + 3145728;             // 1M f16: W_o cast
    f16* Qf  = wof + 1048576;             // 3 x 4M f16: Q | K(swz) | V^T(swz)
    f16* AOf = Qf + (size_t)3 * QKVSZ;    // 4M f16: attention out [M][1024]

    // 0) cast x, W_qkv, W_o to f16
    cvt_kernel<<<dim3(4096), dim3(256), 0, stream>>>(x, W_qkv, W_o, xf, wqf, wof);

    // 1) QKV projection (f16 MFMA, fp32 accum) -> Q/K/V^T attention layouts
    gemm_f16<0><<<dim3(32 * 24), dim3(256), 0, stream>>>(xf, wqf, b_qkv, (void*)Qf, 32);

    // 2) MFMA flash attention
    attn_mfma<<<dim3(32 * 32), dim3(256), 0, stream>>>(Qf, Qf + QKVSZ, Qf + 2 * QKVSZ, AOf);

    // 3) output projection (f16 MFMA, fp32 accum) -> fp32 out
    gemm_f16<1><<<dim3(32 * 8), dim3(256), 0, stream>>>(AOf, wof, b_o, d_out, 32);
}